// Round 2
// baseline (477.371 us; speedup 1.0000x reference)
//
#include <hip/hip_runtime.h>
#include <stdint.h>

typedef __attribute__((ext_vector_type(8))) short bf16x8;
typedef __attribute__((ext_vector_type(4))) short bf16x4;
typedef __attribute__((ext_vector_type(4))) float f32x4;

#define GLB(p) ((__attribute__((address_space(1))) void*)(p))
#define LDSP(p) ((__attribute__((address_space(3))) void*)(p))

__device__ __forceinline__ unsigned short f2bf(float f) {
  union { float f; unsigned u; } v; v.f = f;
  unsigned r = v.u + 0x7fffu + ((v.u >> 16) & 1u);
  return (unsigned short)(r >> 16);
}

// ---- x (fp32, 6291456) -> bf16 ----
__global__ __launch_bounds__(256) void k_convert_x(const float* __restrict__ x,
                                                   unsigned short* __restrict__ X) {
  int i = blockIdx.x * 256 + threadIdx.x;
  float4 v = ((const float4*)x)[i];
  ushort4 o;
  o.x = f2bf(v.x); o.y = f2bf(v.y); o.z = f2bf(v.z); o.w = f2bf(v.w);
  ((ushort4*)X)[i] = o;
}

// ---- transpose 768x768 fp32 -> bf16, dst[c][r] = src[r][c] ----
__global__ __launch_bounds__(256) void k_transpose_w(const float* __restrict__ src,
                                                     unsigned short* __restrict__ dst) {
  __shared__ float t[32][33];
  int tx = threadIdx.x & 31, ty = threadIdx.x >> 5;
  int c0 = blockIdx.x * 32, r0 = blockIdx.y * 32;
  #pragma unroll
  for (int i = 0; i < 4; ++i)
    t[ty + i * 8][tx] = src[(size_t)(r0 + ty + i * 8) * 768 + c0 + tx];
  __syncthreads();
  #pragma unroll
  for (int i = 0; i < 4; ++i)
    dst[(size_t)(c0 + ty + i * 8) * 768 + r0 + tx] = f2bf(t[tx][ty + i * 8]);
}

// ---- transpose V [192][512][64] -> VT [192][64][512] (bf16) ----
__global__ __launch_bounds__(256) void k_transpose_v(const unsigned short* __restrict__ V,
                                                     unsigned short* __restrict__ VT) {
  __shared__ unsigned short t[32][33];
  int tx = threadIdx.x & 31, ty = threadIdx.x >> 5;
  int c0 = blockIdx.x * 32;   // d
  int r0 = blockIdx.y * 32;   // n
  int bh = blockIdx.z;
  const unsigned short* src = V + (size_t)bh * 512 * 64;
  unsigned short* dst = VT + (size_t)bh * 64 * 512;
  #pragma unroll
  for (int i = 0; i < 4; ++i)
    t[ty + i * 8][tx] = src[(r0 + ty + i * 8) * 64 + c0 + tx];
  __syncthreads();
  #pragma unroll
  for (int i = 0; i < 4; ++i)
    dst[(c0 + ty + i * 8) * 512 + r0 + tx] = t[tx][ty + i * 8];
}

// ---- GEMM core: C(128x128 tile) = A(Mx768) * Bt(Nx768)^T, bf16 MFMA ----
template <int EPI>
__global__ __launch_bounds__(256) void k_gemm(
    const unsigned short* __restrict__ A, const unsigned short* __restrict__ Bt,
    const float* __restrict__ b0, const float* __restrict__ b1, const float* __restrict__ b2,
    unsigned short* __restrict__ Qo, unsigned short* __restrict__ Ko,
    unsigned short* __restrict__ Vo, float* __restrict__ Co) {
  __shared__ unsigned short sA[128 * 32];
  __shared__ unsigned short sB[128 * 32];
  const int tid = threadIdx.x, lane = tid & 63, wid = tid >> 6;
  const int wr = wid >> 1, wc = wid & 1;
  const int m0 = blockIdx.y * 128, n0 = blockIdx.x * 128;
  const int lrow = lane >> 2, lkoff = (lane & 3) * 8;
  const int fr = lane & 15, fg = lane >> 4;
  f32x4 acc[4][4] = {};

  for (int k0 = 0; k0 < 768; k0 += 32) {
    #pragma unroll
    for (int it = 0; it < 2; ++it) {
      int rb = it * 64 + wid * 16;
      __builtin_amdgcn_global_load_lds(GLB(A + (size_t)(m0 + rb + lrow) * 768 + k0 + lkoff),
                                       LDSP(sA + rb * 32), 16, 0, 0);
      __builtin_amdgcn_global_load_lds(GLB(Bt + (size_t)(n0 + rb + lrow) * 768 + k0 + lkoff),
                                       LDSP(sB + rb * 32), 16, 0, 0);
    }
    __syncthreads();
    bf16x8 af[4], bw[4];
    #pragma unroll
    for (int f = 0; f < 4; ++f) {
      af[f] = *(const bf16x8*)&sA[(wr * 64 + f * 16 + fr) * 32 + fg * 8];
      bw[f] = *(const bf16x8*)&sB[(wc * 64 + f * 16 + fr) * 32 + fg * 8];
    }
    #pragma unroll
    for (int i = 0; i < 4; ++i)
      #pragma unroll
      for (int j = 0; j < 4; ++j)
        acc[i][j] = __builtin_amdgcn_mfma_f32_16x16x32_bf16(af[i], bw[j], acc[i][j], 0, 0, 0);
    __syncthreads();
  }

  if (EPI == 0) {
    #pragma unroll
    for (int fm = 0; fm < 4; ++fm) {
      int row0 = m0 + wr * 64 + fm * 16;
      int nseq = row0 >> 4;  // B=16: row = n*16 + b
      #pragma unroll
      for (int fn = 0; fn < 4; ++fn) {
        int col = n0 + wc * 64 + fn * 16 + fr;
        int sel = (col >= 1536) ? 2 : (col >= 768) ? 1 : 0;
        int jj = col - sel * 768;
        int h = jj >> 6, d = jj & 63;
        const float* bp = (sel == 0) ? b0 : (sel == 1) ? b1 : b2;
        float bias = bp[jj];
        unsigned short* dst = (sel == 0) ? Qo : (sel == 1) ? Ko : Vo;
        #pragma unroll
        for (int r = 0; r < 4; ++r) {
          int bb = fg * 4 + r;
          dst[(((size_t)bb * 12 + h) * 512 + nseq) * 64 + d] = f2bf(acc[fm][fn][r] + bias);
        }
      }
    }
  } else {
    #pragma unroll
    for (int fm = 0; fm < 4; ++fm) {
      int row0 = m0 + wr * 64 + fm * 16;
      #pragma unroll
      for (int fn = 0; fn < 4; ++fn) {
        int col = n0 + wc * 64 + fn * 16 + fr;
        float bias = b0[col];
        #pragma unroll
        for (int r = 0; r < 4; ++r)
          __builtin_nontemporal_store(acc[fm][fn][r] + bias,
                                      &Co[(size_t)(row0 + fg * 4 + r) * 768 + col]);
      }
    }
  }
}

// ---- attention v2: swapped QK^T, flash-online softmax, per-wave P strip ----
// 1 block = (bh, 64 q rows), 4 waves x 16 q rows. Lane (fg,fr): q-row = q0+fr,
// scores k = t*16 + fg*4 + r (C-layout of mfma(K,Q)). Bias -> float4 loads.
__global__ __launch_bounds__(256) void k_attn(
    const unsigned short* __restrict__ Q, const unsigned short* __restrict__ K,
    const unsigned short* __restrict__ VT, const float* __restrict__ bias,
    const unsigned char* __restrict__ mask, unsigned short* __restrict__ O) {
  __shared__ unsigned short P[4][2][512];  // per-wave 2x1KB strips, no barriers
  const int tid = threadIdx.x, lane = tid & 63, wid = tid >> 6;
  const int bh = blockIdx.x >> 3, qt = blockIdx.x & 7;
  const int b = bh / 12, h = bh - b * 12;
  const int q0 = qt * 64 + wid * 16;
  const int fr = lane & 15, fg = lane >> 4;
  const unsigned short* Qb = Q + (size_t)bh * 512 * 64;
  const unsigned short* Kb = K + (size_t)bh * 512 * 64;
  const unsigned short* Vb = VT + (size_t)bh * 64 * 512;
  const float* biasRow = bias + ((size_t)bh * 512 + q0 + fr) * 512 + fg * 4;
  const unsigned char* mb = mask + b * 512;

  // Q fragment (B-operand): lane holds Q[q0+fr][fg*8 + 0..7]
  bf16x8 aq0 = *(const bf16x8*)&Qb[(q0 + fr) * 64 + fg * 8];
  bf16x8 aq1 = *(const bf16x8*)&Qb[(q0 + fr) * 64 + fg * 8 + 32];

  float m_run = -1e30f, l_run = 0.0f;
  f32x4 o4[4] = {};
  const int swz = (fr & 7) << 3;

  // preload chunk-0 bias (8 x float4 per lane = k 0..127 of this q row)
  f32x4 bv[8];
  #pragma unroll
  for (int t = 0; t < 8; ++t)
    bv[t] = __builtin_nontemporal_load((const f32x4*)(biasRow + t * 16));

  #pragma unroll 1
  for (int c = 0; c < 4; ++c) {
    // QK^T (swapped): 8 t-tiles of 16 k
    float s[8][4];
    #pragma unroll
    for (int t = 0; t < 8; ++t) {
      int kr = (c * 8 + t) * 16 + fr;
      bf16x8 kb0 = *(const bf16x8*)&Kb[kr * 64 + fg * 8];
      bf16x8 kb1 = *(const bf16x8*)&Kb[kr * 64 + fg * 8 + 32];
      f32x4 a = {};
      a = __builtin_amdgcn_mfma_f32_16x16x32_bf16(kb0, aq0, a, 0, 0, 0);
      a = __builtin_amdgcn_mfma_f32_16x16x32_bf16(kb1, aq1, a, 0, 0, 0);
      uchar4 mk = *(const uchar4*)&mb[(c * 8 + t) * 16 + fg * 4];
      s[t][0] = a[0] * 0.125f + bv[t][0] + (mk.x ? -1e30f : 0.0f);
      s[t][1] = a[1] * 0.125f + bv[t][1] + (mk.y ? -1e30f : 0.0f);
      s[t][2] = a[2] * 0.125f + bv[t][2] + (mk.z ? -1e30f : 0.0f);
      s[t][3] = a[3] * 0.125f + bv[t][3] + (mk.w ? -1e30f : 0.0f);
    }
    // prefetch next chunk's bias while softmax+PV run
    if (c < 3) {
      #pragma unroll
      for (int t = 0; t < 8; ++t)
        bv[t] = __builtin_nontemporal_load((const f32x4*)(biasRow + (c + 1) * 128 + t * 16));
    }
    // online softmax: state per q-row (lane-local, replicated over fg after shuffles)
    float cm = s[0][0];
    #pragma unroll
    for (int t = 0; t < 8; ++t)
      #pragma unroll
      for (int r = 0; r < 4; ++r) cm = fmaxf(cm, s[t][r]);
    cm = fmaxf(cm, __shfl_xor(cm, 16));
    cm = fmaxf(cm, __shfl_xor(cm, 32));
    float mnew = fmaxf(m_run, cm);
    float fac = __expf(m_run - mnew);
    float csum = 0.0f;
    #pragma unroll
    for (int t = 0; t < 8; ++t)
      #pragma unroll
      for (int r = 0; r < 4; ++r) {
        float p = __expf(s[t][r] - mnew);
        s[t][r] = p; csum += p;
      }
    csum += __shfl_xor(csum, 16);
    csum += __shfl_xor(csum, 32);
    l_run = l_run * fac + csum;
    m_run = mnew;
    #pragma unroll
    for (int r = 0; r < 4; ++r) {
      float f = __shfl(fac, fg * 4 + r);
      #pragma unroll
      for (int dt = 0; dt < 4; ++dt) o4[dt][r] *= f;
    }
    // P^T -> A-frag redistribution via wave-private LDS strip + PV
    #pragma unroll
    for (int ks = 0; ks < 4; ++ks) {
      unsigned short* Pw = &P[wid][ks & 1][0];
      #pragma unroll
      for (int tp = 0; tp < 2; ++tp) {
        int tl = ks * 2 + tp;
        ushort4 pk4;
        pk4.x = f2bf(s[tl][0]); pk4.y = f2bf(s[tl][1]);
        pk4.z = f2bf(s[tl][2]); pk4.w = f2bf(s[tl][3]);
        *(ushort4*)((char*)Pw + ((fr * 64 + tp * 32 + fg * 8) ^ swz)) = pk4;
      }
      bf16x4 plo = *(const bf16x4*)((char*)Pw + ((fr * 64 + fg * 16) ^ swz));
      bf16x4 phi = *(const bf16x4*)((char*)Pw + ((fr * 64 + fg * 16 + 8) ^ swz));
      bf16x8 pa = __builtin_shufflevector(plo, phi, 0, 1, 2, 3, 4, 5, 6, 7);
      int kglob = c * 128 + ks * 32;
      #pragma unroll
      for (int dt = 0; dt < 4; ++dt) {
        bf16x8 vb = *(const bf16x8*)&Vb[(size_t)(dt * 16 + fr) * 512 + kglob + fg * 8];
        o4[dt] = __builtin_amdgcn_mfma_f32_16x16x32_bf16(pa, vb, o4[dt], 0, 0, 0);
      }
    }
  }

  float inv = 1.0f / l_run;
  #pragma unroll
  for (int r = 0; r < 4; ++r) {
    float iv = __shfl(inv, fg * 4 + r);
    #pragma unroll
    for (int dt = 0; dt < 4; ++dt)
      O[(size_t)((q0 + fg * 4 + r) * 16 + b) * 768 + h * 64 + dt * 16 + fr] =
          f2bf(o4[dt][r] * iv);
  }
}

extern "C" void kernel_launch(void* const* d_in, const int* in_sizes, int n_in,
                              void* d_out, int out_size, void* d_ws, size_t ws_size,
                              hipStream_t stream) {
  const float* x = (const float*)d_in[0];
  const float* ab = (const float*)d_in[1];
  const unsigned char* mask = (const unsigned char*)d_in[2];
  const float* Wq = (const float*)d_in[3];
  const float* bq = (const float*)d_in[4];
  const float* Wk = (const float*)d_in[5];
  const float* bk = (const float*)d_in[6];
  const float* Wv = (const float*)d_in[7];
  const float* bv = (const float*)d_in[8];
  const float* Wo = (const float*)d_in[9];
  const float* bo = (const float*)d_in[10];
  float* out = (float*)d_out;

  char* w = (char*)d_ws;
  unsigned short* X   = (unsigned short*)(w);              // 12582912 B ; reused as O
  unsigned short* WTq = (unsigned short*)(w + 12582912);   // 3538944 B (2304x768)
  unsigned short* WoT = (unsigned short*)(w + 16121856);   // 1179648 B
  unsigned short* Qb  = (unsigned short*)(w + 17301504);   // 12582912 B
  unsigned short* Kb  = (unsigned short*)(w + 29884416);   // 12582912 B
  unsigned short* Vn  = (unsigned short*)(w + 42467328);   // 12582912 B
  unsigned short* VT  = (unsigned short*)(w + 55050240);   // 12582912 B -> end 67633152
  unsigned short* O   = X;  // x dead after QKV GEMM

  k_convert_x<<<6144, 256, 0, stream>>>(x, X);
  dim3 tg(24, 24);
  k_transpose_w<<<tg, 256, 0, stream>>>(Wq, WTq);
  k_transpose_w<<<tg, 256, 0, stream>>>(Wk, WTq + 768 * 768);
  k_transpose_w<<<tg, 256, 0, stream>>>(Wv, WTq + 2 * 768 * 768);
  k_transpose_w<<<tg, 256, 0, stream>>>(Wo, WoT);
  k_gemm<0><<<dim3(18, 64), 256, 0, stream>>>(X, WTq, bq, bk, bv, Qb, Kb, Vn, nullptr);
  k_transpose_v<<<dim3(2, 16, 192), 256, 0, stream>>>(Vn, VT);
  k_attn<<<1536, 256, 0, stream>>>(Qb, Kb, VT, ab, mask, O);
  k_gemm<1><<<dim3(6, 64), 256, 0, stream>>>(O, WoT, bo, nullptr, nullptr, nullptr, nullptr, nullptr, out);
}

// Round 3
// 422.676 us; speedup vs baseline: 1.1294x; 1.1294x over previous
//
#include <hip/hip_runtime.h>
#include <stdint.h>

typedef __attribute__((ext_vector_type(8))) short bf16x8;
typedef __attribute__((ext_vector_type(4))) short bf16x4;
typedef __attribute__((ext_vector_type(4))) float f32x4;

#define GLB(p) ((__attribute__((address_space(1))) void*)(p))
#define LDSP(p) ((__attribute__((address_space(3))) void*)(p))

__device__ __forceinline__ unsigned short f2bf(float f) {
  union { float f; unsigned u; } v; v.f = f;
  unsigned r = v.u + 0x7fffu + ((v.u >> 16) & 1u);
  return (unsigned short)(r >> 16);
}

// ---- x (fp32, 6291456) -> bf16 ----
__global__ __launch_bounds__(256) void k_convert_x(const float* __restrict__ x,
                                                   unsigned short* __restrict__ X) {
  int i = blockIdx.x * 256 + threadIdx.x;
  float4 v = ((const float4*)x)[i];
  ushort4 o;
  o.x = f2bf(v.x); o.y = f2bf(v.y); o.z = f2bf(v.z); o.w = f2bf(v.w);
  ((ushort4*)X)[i] = o;
}

// ---- transpose 768x768 fp32 -> bf16, dst[c][r] = src[r][c] ----
__global__ __launch_bounds__(256) void k_transpose_w(const float* __restrict__ src,
                                                     unsigned short* __restrict__ dst) {
  __shared__ float t[32][33];
  int tx = threadIdx.x & 31, ty = threadIdx.x >> 5;
  int c0 = blockIdx.x * 32, r0 = blockIdx.y * 32;
  #pragma unroll
  for (int i = 0; i < 4; ++i)
    t[ty + i * 8][tx] = src[(size_t)(r0 + ty + i * 8) * 768 + c0 + tx];
  __syncthreads();
  #pragma unroll
  for (int i = 0; i < 4; ++i)
    dst[(size_t)(c0 + ty + i * 8) * 768 + r0 + tx] = f2bf(t[tx][ty + i * 8]);
}

// ---- transpose V [192][512][64] -> VT [192][64][512] (bf16) ----
__global__ __launch_bounds__(256) void k_transpose_v(const unsigned short* __restrict__ V,
                                                     unsigned short* __restrict__ VT) {
  __shared__ unsigned short t[32][33];
  int tx = threadIdx.x & 31, ty = threadIdx.x >> 5;
  int c0 = blockIdx.x * 32;   // d
  int r0 = blockIdx.y * 32;   // n
  int bh = blockIdx.z;
  const unsigned short* src = V + (size_t)bh * 512 * 64;
  unsigned short* dst = VT + (size_t)bh * 64 * 512;
  #pragma unroll
  for (int i = 0; i < 4; ++i)
    t[ty + i * 8][tx] = src[(r0 + ty + i * 8) * 64 + c0 + tx];
  __syncthreads();
  #pragma unroll
  for (int i = 0; i < 4; ++i)
    dst[(c0 + ty + i * 8) * 512 + r0 + tx] = t[tx][ty + i * 8];
}

// ---- GEMM core: C(128x128 tile) = A(Mx768) * Bt(Nx768)^T, bf16 MFMA ----
template <int EPI>
__global__ __launch_bounds__(256) void k_gemm(
    const unsigned short* __restrict__ A, const unsigned short* __restrict__ Bt,
    const float* __restrict__ b0, const float* __restrict__ b1, const float* __restrict__ b2,
    unsigned short* __restrict__ Qo, unsigned short* __restrict__ Ko,
    unsigned short* __restrict__ Vo, float* __restrict__ Co) {
  __shared__ unsigned short sA[128 * 32];
  __shared__ unsigned short sB[128 * 32];
  const int tid = threadIdx.x, lane = tid & 63, wid = tid >> 6;
  const int wr = wid >> 1, wc = wid & 1;
  const int m0 = blockIdx.y * 128, n0 = blockIdx.x * 128;
  const int lrow = lane >> 2, lkoff = (lane & 3) * 8;
  const int fr = lane & 15, fg = lane >> 4;
  f32x4 acc[4][4] = {};

  for (int k0 = 0; k0 < 768; k0 += 32) {
    #pragma unroll
    for (int it = 0; it < 2; ++it) {
      int rb = it * 64 + wid * 16;
      __builtin_amdgcn_global_load_lds(GLB(A + (size_t)(m0 + rb + lrow) * 768 + k0 + lkoff),
                                       LDSP(sA + rb * 32), 16, 0, 0);
      __builtin_amdgcn_global_load_lds(GLB(Bt + (size_t)(n0 + rb + lrow) * 768 + k0 + lkoff),
                                       LDSP(sB + rb * 32), 16, 0, 0);
    }
    __syncthreads();
    bf16x8 af[4], bw[4];
    #pragma unroll
    for (int f = 0; f < 4; ++f) {
      af[f] = *(const bf16x8*)&sA[(wr * 64 + f * 16 + fr) * 32 + fg * 8];
      bw[f] = *(const bf16x8*)&sB[(wc * 64 + f * 16 + fr) * 32 + fg * 8];
    }
    #pragma unroll
    for (int i = 0; i < 4; ++i)
      #pragma unroll
      for (int j = 0; j < 4; ++j)
        acc[i][j] = __builtin_amdgcn_mfma_f32_16x16x32_bf16(af[i], bw[j], acc[i][j], 0, 0, 0);
    __syncthreads();
  }

  if (EPI == 0) {
    #pragma unroll
    for (int fm = 0; fm < 4; ++fm) {
      int row0 = m0 + wr * 64 + fm * 16;
      int nseq = row0 >> 4;  // B=16: row = n*16 + b
      #pragma unroll
      for (int fn = 0; fn < 4; ++fn) {
        int col = n0 + wc * 64 + fn * 16 + fr;
        int sel = (col >= 1536) ? 2 : (col >= 768) ? 1 : 0;
        int jj = col - sel * 768;
        int h = jj >> 6, d = jj & 63;
        const float* bp = (sel == 0) ? b0 : (sel == 1) ? b1 : b2;
        float bias = bp[jj];
        unsigned short* dst = (sel == 0) ? Qo : (sel == 1) ? Ko : Vo;
        #pragma unroll
        for (int r = 0; r < 4; ++r) {
          int bb = fg * 4 + r;
          dst[(((size_t)bb * 12 + h) * 512 + nseq) * 64 + d] = f2bf(acc[fm][fn][r] + bias);
        }
      }
    }
  } else {
    #pragma unroll
    for (int fm = 0; fm < 4; ++fm) {
      int row0 = m0 + wr * 64 + fm * 16;
      #pragma unroll
      for (int fn = 0; fn < 4; ++fn) {
        int col = n0 + wc * 64 + fn * 16 + fr;
        float bias = b0[col];
        #pragma unroll
        for (int r = 0; r < 4; ++r)
          __builtin_nontemporal_store(acc[fm][fn][r] + bias,
                                      &Co[(size_t)(row0 + fg * 4 + r) * 768 + col]);
      }
    }
  }
}

// ---- attention v3: all operands via global_load_lds DMA pipeline ----
// Block = (bh, 64 q rows), 4 waves x 16 q. 8 chunks of 64 k, double-buffered.
// Compute phase has ZERO direct global loads (vmcnt belongs to DMA only).
// LDS layouts XOR-swizzled; swizzle applied to DMA *source* addr (linear dest)
// and to the read addr (same involution). bh = bx%192 -> all 8 q-tiles of one
// head land on one XCD => K/V stay L2-resident (3 MB/XCD < 4 MB).
__global__ __launch_bounds__(256) void k_attn(
    const unsigned short* __restrict__ Q, const unsigned short* __restrict__ K,
    const unsigned short* __restrict__ VT, const float* __restrict__ bias,
    const unsigned char* __restrict__ mask, unsigned short* __restrict__ O) {
  __shared__ float biasS[2][4096];           // 32 KB : [64 q][16 slot][4 f32]
  __shared__ unsigned short Ks[2][4096];     // 16 KB : [64 kr][8 slot][8 bf16]
  __shared__ unsigned short Vs[2][4096];     // 16 KB : [64 d ][8 slot][8 bf16]
  __shared__ unsigned short Pst[4][2][512];  // 8 KB per-wave P strips
  __shared__ unsigned char mS[512];

  const int tid = threadIdx.x, lane = tid & 63, wid = tid >> 6;
  const int bh = blockIdx.x % 192, qt = blockIdx.x / 192;
  const int b = bh / 12, h = bh - b * 12;
  const int q0 = qt * 64 + wid * 16;
  const int fr = lane & 15, fg = lane >> 4;
  const int l15 = lane & 15, l7 = lane & 7;

  const unsigned short* Qb = Q + (size_t)bh * 512 * 64;
  const char* Kg = (const char*)(K + (size_t)bh * 512 * 64);
  const char* Vg = (const char*)(VT + (size_t)bh * 64 * 512);
  const char* Bg = (const char*)(bias + ((size_t)bh * 512 + qt * 64) * 512);

  if (tid < 128) ((uint32_t*)mS)[tid] = ((const uint32_t*)(mask + b * 512))[tid];

  bf16x8 aq0 = *(const bf16x8*)&Qb[(q0 + fr) * 64 + fg * 8];
  bf16x8 aq1 = *(const bf16x8*)&Qb[(q0 + fr) * 64 + fg * 8 + 32];

  auto issue = [&](int c) {
    int pb = c & 1;
    char* bB = (char*)&biasS[pb][0];
    char* kB = (char*)&Ks[pb][0];
    char* vB = (char*)&Vs[pb][0];
    #pragma unroll
    for (int jj = 0; jj < 4; ++jj) {       // bias: 4 rows x 256B per DMA
      int j = wid * 4 + jj;
      int ql = j * 4 + (lane >> 4);
      __builtin_amdgcn_global_load_lds(
          GLB(Bg + (size_t)ql * 2048 + c * 256 + ((l15 ^ (ql & 15)) << 4)),
          LDSP(bB + j * 1024), 16, 0, 0);
    }
    #pragma unroll
    for (int jj = 0; jj < 2; ++jj) {       // K,V: 8 rows x 128B per DMA
      int j = wid * 2 + jj;
      int rl = j * 8 + (lane >> 3);
      __builtin_amdgcn_global_load_lds(
          GLB(Kg + (size_t)(c * 64 + rl) * 128 + ((l7 ^ (rl & 7)) << 4)),
          LDSP(kB + j * 1024), 16, 0, 0);
      __builtin_amdgcn_global_load_lds(
          GLB(Vg + (size_t)rl * 1024 + c * 128 + ((l7 ^ (rl & 7)) << 4)),
          LDSP(vB + j * 1024), 16, 0, 0);
    }
  };

  float m_run = -1e30f, l_run = 0.0f;
  f32x4 o4[4] = {};
  const int swz = (fr & 7) << 3;

  issue(0);

  #pragma unroll 1
  for (int c = 0; c < 8; ++c) {
    __syncthreads();                 // drains DMA(c), publishes LDS
    if (c < 7) issue(c + 1);         // full compute window to land
    int pb = c & 1;
    const char* Kl = (const char*)&Ks[pb][0];
    const char* Vl = (const char*)&Vs[pb][0];
    const char* Bl = (const char*)&biasS[pb][0];

    float s[4][4];
    #pragma unroll
    for (int t = 0; t < 4; ++t) {
      int kr = t * 16 + fr;
      bf16x8 kb0 = *(const bf16x8*)(Kl + kr * 128 + ((fg ^ (fr & 7)) << 4));
      bf16x8 kb1 = *(const bf16x8*)(Kl + kr * 128 + (((fg + 4) ^ (fr & 7)) << 4));
      f32x4 a = {};
      a = __builtin_amdgcn_mfma_f32_16x16x32_bf16(kb0, aq0, a, 0, 0, 0);
      a = __builtin_amdgcn_mfma_f32_16x16x32_bf16(kb1, aq1, a, 0, 0, 0);
      f32x4 bvv = *(const f32x4*)(Bl + (wid * 16 + fr) * 256 + (((t * 4 + fg) ^ fr) << 4));
      uchar4 mk = *(const uchar4*)&mS[c * 64 + t * 16 + fg * 4];
      s[t][0] = a[0] * 0.125f + bvv[0] + (mk.x ? -1e30f : 0.0f);
      s[t][1] = a[1] * 0.125f + bvv[1] + (mk.y ? -1e30f : 0.0f);
      s[t][2] = a[2] * 0.125f + bvv[2] + (mk.z ? -1e30f : 0.0f);
      s[t][3] = a[3] * 0.125f + bvv[3] + (mk.w ? -1e30f : 0.0f);
    }

    float cm = s[0][0];
    #pragma unroll
    for (int t = 0; t < 4; ++t)
      #pragma unroll
      for (int r = 0; r < 4; ++r) cm = fmaxf(cm, s[t][r]);
    cm = fmaxf(cm, __shfl_xor(cm, 16));
    cm = fmaxf(cm, __shfl_xor(cm, 32));
    float mnew = fmaxf(m_run, cm);
    float fac = __expf(m_run - mnew);
    float csum = 0.0f;
    #pragma unroll
    for (int t = 0; t < 4; ++t)
      #pragma unroll
      for (int r = 0; r < 4; ++r) {
        float p = __expf(s[t][r] - mnew);
        s[t][r] = p; csum += p;
      }
    csum += __shfl_xor(csum, 16);
    csum += __shfl_xor(csum, 32);
    l_run = l_run * fac + csum;
    m_run = mnew;
    #pragma unroll
    for (int r = 0; r < 4; ++r) {
      float f = __shfl(fac, fg * 4 + r);
      #pragma unroll
      for (int dt = 0; dt < 4; ++dt) o4[dt][r] *= f;
    }

    #pragma unroll
    for (int g = 0; g < 2; ++g) {
      unsigned short* Pw = &Pst[wid][g][0];
      #pragma unroll
      for (int tp = 0; tp < 2; ++tp) {
        int tl = g * 2 + tp;
        ushort4 pk4;
        pk4.x = f2bf(s[tl][0]); pk4.y = f2bf(s[tl][1]);
        pk4.z = f2bf(s[tl][2]); pk4.w = f2bf(s[tl][3]);
        *(ushort4*)((char*)Pw + ((fr * 64 + tp * 32 + fg * 8) ^ swz)) = pk4;
      }
      bf16x4 plo = *(const bf16x4*)((char*)Pw + ((fr * 64 + fg * 16) ^ swz));
      bf16x4 phi = *(const bf16x4*)((char*)Pw + ((fr * 64 + fg * 16 + 8) ^ swz));
      bf16x8 pa = __builtin_shufflevector(plo, phi, 0, 1, 2, 3, 4, 5, 6, 7);
      #pragma unroll
      for (int dt = 0; dt < 4; ++dt) {
        bf16x8 vb = *(const bf16x8*)(Vl + (dt * 16 + fr) * 128 + (((g * 4 + fg) ^ (fr & 7)) << 4));
        o4[dt] = __builtin_amdgcn_mfma_f32_16x16x32_bf16(pa, vb, o4[dt], 0, 0, 0);
      }
    }
  }

  float inv = 1.0f / l_run;
  #pragma unroll
  for (int r = 0; r < 4; ++r) {
    float iv = __shfl(inv, fg * 4 + r);
    #pragma unroll
    for (int dt = 0; dt < 4; ++dt)
      O[(size_t)((q0 + fg * 4 + r) * 16 + b) * 768 + h * 64 + dt * 16 + fr] =
          f2bf(o4[dt][r] * iv);
  }
}

extern "C" void kernel_launch(void* const* d_in, const int* in_sizes, int n_in,
                              void* d_out, int out_size, void* d_ws, size_t ws_size,
                              hipStream_t stream) {
  const float* x = (const float*)d_in[0];
  const float* ab = (const float*)d_in[1];
  const unsigned char* mask = (const unsigned char*)d_in[2];
  const float* Wq = (const float*)d_in[3];
  const float* bq = (const float*)d_in[4];
  const float* Wk = (const float*)d_in[5];
  const float* bk = (const float*)d_in[6];
  const float* Wv = (const float*)d_in[7];
  const float* bv = (const float*)d_in[8];
  const float* Wo = (const float*)d_in[9];
  const float* bo = (const float*)d_in[10];
  float* out = (float*)d_out;

  char* w = (char*)d_ws;
  unsigned short* X   = (unsigned short*)(w);              // 12582912 B ; reused as O
  unsigned short* WTq = (unsigned short*)(w + 12582912);   // 3538944 B (2304x768)
  unsigned short* WoT = (unsigned short*)(w + 16121856);   // 1179648 B
  unsigned short* Qb  = (unsigned short*)(w + 17301504);   // 12582912 B
  unsigned short* Kb  = (unsigned short*)(w + 29884416);   // 12582912 B
  unsigned short* Vn  = (unsigned short*)(w + 42467328);   // 12582912 B
  unsigned short* VT  = (unsigned short*)(w + 55050240);   // 12582912 B -> end 67633152
  unsigned short* O   = X;  // x dead after QKV GEMM

  k_convert_x<<<6144, 256, 0, stream>>>(x, X);
  dim3 tg(24, 24);
  k_transpose_w<<<tg, 256, 0, stream>>>(Wq, WTq);
  k_transpose_w<<<tg, 256, 0, stream>>>(Wk, WTq + 768 * 768);
  k_transpose_w<<<tg, 256, 0, stream>>>(Wv, WTq + 2 * 768 * 768);
  k_transpose_w<<<tg, 256, 0, stream>>>(Wo, WoT);
  k_gemm<0><<<dim3(18, 64), 256, 0, stream>>>(X, WTq, bq, bk, bv, Qb, Kb, Vn, nullptr);
  k_transpose_v<<<dim3(2, 16, 192), 256, 0, stream>>>(Vn, VT);
  k_attn<<<1536, 256, 0, stream>>>(Qb, Kb, VT, ab, mask, O);
  k_gemm<1><<<dim3(6, 64), 256, 0, stream>>>(O, WoT, bo, nullptr, nullptr, nullptr, nullptr, nullptr, out);
}